// Round 1
// baseline (18378.198 us; speedup 1.0000x reference)
//
#include <hip/hip_runtime.h>
#include <hip/hip_cooperative_groups.h>

namespace cg = cooperative_groups;

static constexpr int Bc = 128;   // batch
static constexpr int Tc = 256;   // timesteps
static constexpr int Ec = 512;   // input embed
static constexpr int Hc = 1024;  // hidden
static constexpr int K2c = 2048; // concat K for recurrent layers

using bf16x8 = __attribute__((ext_vector_type(8))) short;
using f32x4  = __attribute__((ext_vector_type(4))) float;

__device__ __forceinline__ unsigned short f2bf(float f) {
  unsigned int u = __float_as_uint(f);
  u += 0x7FFFu + ((u >> 16) & 1u);
  return (unsigned short)(u >> 16);
}
__device__ __forceinline__ float sigm(float x) { return 1.0f / (1.0f + __expf(-x)); }

#define MFMA16(A, Bf, C) __builtin_amdgcn_mfma_f32_16x16x32_bf16((A), (Bf), (C), 0, 0, 0)

// ----------------- prep kernels -----------------
__global__ void k_cvt_bf16(const float* __restrict__ src, unsigned short* __restrict__ dst, int n) {
  int i = (blockIdx.x * blockDim.x + threadIdx.x) * 4;
  if (i + 3 < n) {
    f32x4 v = *(const f32x4*)(src + i);
    *(ushort4*)(dst + i) = make_ushort4(f2bf(v[0]), f2bf(v[1]), f2bf(v[2]), f2bf(v[3]));
  }
}

// dst[r][k] (bf16, [4096][2048]) = k<1024 ? wih[r][k] : whh[r][k-1024]
__global__ void k_pack_cat(const float* __restrict__ wih, const float* __restrict__ whh,
                           unsigned short* __restrict__ dst) {
  int i = (blockIdx.x * blockDim.x + threadIdx.x) * 4;  // over 4096*2048
  int r = i >> 11;
  int k = i & (K2c - 1);
  const float* s = (k < Hc) ? (wih + (size_t)r * Hc + k) : (whh + (size_t)r * Hc + (k - Hc));
  f32x4 v = *(const f32x4*)s;
  *(ushort4*)(dst + i) = make_ushort4(f2bf(v[0]), f2bf(v[1]), f2bf(v[2]), f2bf(v[3]));
}

__global__ void k_prep_small(const float* __restrict__ bih0, const float* __restrict__ bhh0,
                             const float* __restrict__ bihr, const float* __restrict__ bhhr,
                             float* __restrict__ b0s, float* __restrict__ b1s, float* __restrict__ b2s,
                             unsigned short* __restrict__ h1buf, unsigned short* __restrict__ h2buf,
                             float* __restrict__ c1, float* __restrict__ c2) {
  int i = blockIdx.x * blockDim.x + threadIdx.x;  // 0 .. 262143
  if (i < 4096) {
    b0s[i] = bih0[i] + bhh0[i];
    b1s[i] = bihr[i] + bhhr[i];
    b2s[i] = bihr[4096 + i] + bhhr[4096 + i];
  }
  h1buf[i] = 0; h2buf[i] = 0;               // 2*Bc*Hc = 262144 each
  if (i < Bc * Hc) { c1[i] = 0.0f; c2[i] = 0.0f; }
}

// ----------------- layer-0 bulk GEMM (no recurrence; f-gate dead) -----------------
// rows r = t*Bc + b over all 32768 (t,b); H0[r][j] bf16
__global__ __launch_bounds__(512, 1) void k_l0(
    const float* __restrict__ x, const unsigned short* __restrict__ W0,
    const float* __restrict__ b0s, unsigned short* __restrict__ H0)
{
  const int tid = threadIdx.x;
  const int lane = tid & 63, wid = tid >> 6;
  const int wM = wid >> 2, wN = wid & 3;           // 8 waves: 2(M) x 4(N)
  const int rowbase = blockIdx.x * 32 + wM * 16;   // 1024 x-tiles of 32 rows
  const int jbase   = blockIdx.y * 64 + wN * 16;   // 16 y-tiles of 64 hidden
  const int ri = lane & 15, kg = lane >> 4;

  const int r = rowbase + ri;
  const int t = r >> 7, b = r & (Bc - 1);
  const float* arow = x + ((size_t)b * Tc + t) * Ec + kg * 8;

  const unsigned short* w0r = W0 + ((size_t)(0 * Hc + jbase + ri)) * Ec + kg * 8;
  const unsigned short* w2r = W0 + ((size_t)(2 * Hc + jbase + ri)) * Ec + kg * 8;
  const unsigned short* w3r = W0 + ((size_t)(3 * Hc + jbase + ri)) * Ec + kg * 8;

  f32x4 ai = {0,0,0,0}, ag = {0,0,0,0}, ao = {0,0,0,0};
#pragma unroll 4
  for (int kk = 0; kk < Ec / 32; ++kk) {
    f32x4 x0 = *(const f32x4*)(arow + kk * 32);
    f32x4 x1 = *(const f32x4*)(arow + kk * 32 + 4);
    bf16x8 a;
    a[0] = (short)f2bf(x0[0]); a[1] = (short)f2bf(x0[1]);
    a[2] = (short)f2bf(x0[2]); a[3] = (short)f2bf(x0[3]);
    a[4] = (short)f2bf(x1[0]); a[5] = (short)f2bf(x1[1]);
    a[6] = (short)f2bf(x1[2]); a[7] = (short)f2bf(x1[3]);
    ai = MFMA16(a, *(const bf16x8*)(w0r + kk * 32), ai);
    ag = MFMA16(a, *(const bf16x8*)(w2r + kk * 32), ag);
    ao = MFMA16(a, *(const bf16x8*)(w3r + kk * 32), ao);
  }
  const int j = jbase + ri;
  const float bi = b0s[j], bg = b0s[2 * Hc + j], bo = b0s[3 * Hc + j];
#pragma unroll
  for (int q = 0; q < 4; ++q) {
    const int rr = rowbase + kg * 4 + q;             // C row = (lane>>4)*4 + reg
    float c = sigm(ai[q] + bi) * tanhf(ag[q] + bg);  // c_prev = 0
    float h = sigm(ao[q] + bo) * tanhf(c);
    H0[(size_t)rr * Hc + j] = f2bf(h);
  }
}

// ----------------- recurrent cooperative kernel -----------------
// 256 WGs x 256 thr. WGs 0..127: layer1 (computes h1(p)); 128..255: layer2 (computes h2(p-1)).
// One grid.sync per phase; 257 phases.
__global__ __launch_bounds__(256, 1) void k_rec(
    const unsigned short* H0,                        // [Tc*Bc][Hc] bf16 (upper half of d_out)
    const unsigned short* __restrict__ W1, const unsigned short* __restrict__ W2,
    const float* __restrict__ b1s, const float* __restrict__ b2s,
    unsigned short* __restrict__ h1buf, unsigned short* __restrict__ h2buf,  // [2][Bc][Hc] bf16
    float* __restrict__ c1, float* __restrict__ c2,  // [Bc][Hc] f32
    float* out)                                      // [Tc][Bc][Hc] f32 (lower d_out)
{
  cg::grid_group grid = cg::this_grid();
  const int tid = threadIdx.x;
  const int lane = tid & 63, wid = tid >> 6;
  const int wM = wid >> 1, wN = wid & 1;             // 4 waves: 2(M) x 2(N)
  const int bid = blockIdx.x;
  const int layer = bid >> 7;
  const int v = bid & 127;
  const int mt = v >> 5, jt = v & 31;
  const int rowbase = mt * 32 + wM * 16;             // batch rows
  const int jbase   = jt * 32 + wN * 16;             // hidden cols
  const int ri = lane & 15, kg = lane >> 4;
  const int b = rowbase + ri;                        // A row this lane loads
  const int j = jbase + ri;                          // W row / C col this lane

  const unsigned short* W = layer ? W2 : W1;
  const float* bs = layer ? b2s : b1s;
  float* cst = layer ? c2 : c1;

  const unsigned short* wr0 = W + ((size_t)(0 * Hc + j)) * K2c + kg * 8;
  const unsigned short* wr1 = W + ((size_t)(1 * Hc + j)) * K2c + kg * 8;
  const unsigned short* wr2 = W + ((size_t)(2 * Hc + j)) * K2c + kg * 8;
  const unsigned short* wr3 = W + ((size_t)(3 * Hc + j)) * K2c + kg * 8;
  const float bi = bs[j], bf_ = bs[Hc + j], bg = bs[2 * Hc + j], bo = bs[3 * Hc + j];

  for (int p = 0; p <= Tc; ++p) {
    const int cur = p & 1, prev = cur ^ 1;
    const bool act = (layer == 0) ? (p < Tc) : (p >= 1);
    if (act) {
      const unsigned short* A1;
      const unsigned short* A2;
      if (layer == 0) {
        A1 = H0 + (size_t)p * Bc * Hc;               // h0(p)
        A2 = h1buf + (size_t)prev * Bc * Hc;         // h1(p-1)
      } else {
        A1 = h1buf + (size_t)prev * Bc * Hc;         // h1(p-1)
        A2 = h2buf + (size_t)prev * Bc * Hc;         // h2(p-2)
      }
      const unsigned short* a1 = A1 + (size_t)b * Hc + kg * 8;
      const unsigned short* a2 = A2 + (size_t)b * Hc + kg * 8;
      f32x4 gi4 = {0,0,0,0}, gf4 = {0,0,0,0}, gg4 = {0,0,0,0}, go4 = {0,0,0,0};
#pragma unroll 8
      for (int kk = 0; kk < 32; ++kk) {              // K 0..1023
        bf16x8 a = *(const bf16x8*)(a1 + kk * 32);
        gi4 = MFMA16(a, *(const bf16x8*)(wr0 + kk * 32), gi4);
        gf4 = MFMA16(a, *(const bf16x8*)(wr1 + kk * 32), gf4);
        gg4 = MFMA16(a, *(const bf16x8*)(wr2 + kk * 32), gg4);
        go4 = MFMA16(a, *(const bf16x8*)(wr3 + kk * 32), go4);
      }
#pragma unroll 8
      for (int kk = 0; kk < 32; ++kk) {              // K 1024..2047
        bf16x8 a = *(const bf16x8*)(a2 + kk * 32);
        gi4 = MFMA16(a, *(const bf16x8*)(wr0 + Hc + kk * 32), gi4);
        gf4 = MFMA16(a, *(const bf16x8*)(wr1 + Hc + kk * 32), gf4);
        gg4 = MFMA16(a, *(const bf16x8*)(wr2 + Hc + kk * 32), gg4);
        go4 = MFMA16(a, *(const bf16x8*)(wr3 + Hc + kk * 32), go4);
      }
#pragma unroll
      for (int q = 0; q < 4; ++q) {
        const int rr = rowbase + kg * 4 + q;
        const size_t sidx = (size_t)rr * Hc + j;
        float cn = sigm(gf4[q] + bf_) * cst[sidx] + sigm(gi4[q] + bi) * tanhf(gg4[q] + bg);
        float hn = sigm(go4[q] + bo) * tanhf(cn);
        cst[sidx] = cn;
        if (layer == 0) {
          h1buf[(size_t)cur * Bc * Hc + sidx] = f2bf(hn);
        } else {
          h2buf[(size_t)cur * Bc * Hc + sidx] = f2bf(hn);
          out[(size_t)(p - 1) * Bc * Hc + sidx] = hn;   // out[t][b][h], t = p-1
        }
      }
    }
    grid.sync();
  }
}

// ----------------- launcher -----------------
extern "C" void kernel_launch(void* const* d_in, const int* in_sizes, int n_in,
                              void* d_out, int out_size, void* d_ws, size_t ws_size,
                              hipStream_t stream) {
  const float* x     = (const float*)d_in[0];
  const float* W_ih0 = (const float*)d_in[1];
  // d_in[2] = W_hh0 (unused: layer-0 state is always zero)
  const float* b_ih0 = (const float*)d_in[3];
  const float* b_hh0 = (const float*)d_in[4];
  const float* W_ihr = (const float*)d_in[5];
  const float* W_hhr = (const float*)d_in[6];
  const float* b_ihr = (const float*)d_in[7];
  const float* b_hhr = (const float*)d_in[8];

  char* ws = (char*)d_ws;
  constexpr size_t W0B_OFF = 0;                                  // 4096*512*2
  constexpr size_t W1C_OFF = W0B_OFF + (size_t)4096 * 512 * 2;   // 4096*2048*2
  constexpr size_t W2C_OFF = W1C_OFF + (size_t)4096 * 2048 * 2;
  constexpr size_t B0S_OFF = W2C_OFF + (size_t)4096 * 2048 * 2;
  constexpr size_t B1S_OFF = B0S_OFF + 4096 * 4;
  constexpr size_t B2S_OFF = B1S_OFF + 4096 * 4;
  constexpr size_t H1B_OFF = B2S_OFF + 4096 * 4;                 // 2*128*1024*2
  constexpr size_t H2B_OFF = H1B_OFF + (size_t)2 * Bc * Hc * 2;
  constexpr size_t C1_OFF  = H2B_OFF + (size_t)2 * Bc * Hc * 2;  // 128*1024*4
  constexpr size_t C2_OFF  = C1_OFF + (size_t)Bc * Hc * 4;

  unsigned short* W0b = (unsigned short*)(ws + W0B_OFF);
  unsigned short* W1c = (unsigned short*)(ws + W1C_OFF);
  unsigned short* W2c = (unsigned short*)(ws + W2C_OFF);
  float* b0s = (float*)(ws + B0S_OFF);
  float* b1s = (float*)(ws + B1S_OFF);
  float* b2s = (float*)(ws + B2S_OFF);
  unsigned short* h1buf = (unsigned short*)(ws + H1B_OFF);
  unsigned short* h2buf = (unsigned short*)(ws + H2B_OFF);
  float* c1 = (float*)(ws + C1_OFF);
  float* c2 = (float*)(ws + C2_OFF);

  // H0 (bf16 [T][B][H], 64 MB) lives in the upper half of d_out; out fp32 fills
  // from the front. Writes of out[t'] (phase t'+1) only touch H0[q] bytes for
  // phases >= 129+q/2 > q, strictly after H0[q]'s last read (phase q). Verified
  // byte-exact, including the p==256 tail.
  unsigned short* H0 = (unsigned short*)d_out + (size_t)Tc * Bc * Hc;
  float* out = (float*)d_out;

  int n0 = 4096 * 512;
  k_cvt_bf16<<<n0 / 1024, 256, 0, stream>>>(W_ih0, W0b, n0);
  k_pack_cat<<<8192, 256, 0, stream>>>(W_ihr, W_hhr, W1c);
  k_pack_cat<<<8192, 256, 0, stream>>>(W_ihr + (size_t)4096 * 1024, W_hhr + (size_t)4096 * 1024, W2c);
  k_prep_small<<<1024, 256, 0, stream>>>(b_ih0, b_hh0, b_ihr, b_hhr,
                                         b0s, b1s, b2s, h1buf, h2buf, c1, c2);
  k_l0<<<dim3(1024, 16), 512, 0, stream>>>(x, W0b, b0s, H0);

  void* kargs[] = { &H0, &W1c, &W2c, &b1s, &b2s, &h1buf, &h2buf, &c1, &c2, &out };
  hipLaunchCooperativeKernel((void*)k_rec, dim3(256), dim3(256), kargs, 0, stream);
}

// Round 2
// 12248.896 us; speedup vs baseline: 1.5004x; 1.5004x over previous
//
#include <hip/hip_runtime.h>
#include <hip/hip_cooperative_groups.h>

namespace cg = cooperative_groups;

static constexpr int Bc = 128;   // batch
static constexpr int Tc = 256;   // timesteps
static constexpr int Ec = 512;   // input embed
static constexpr int Hc = 1024;  // hidden

using bf16x8 = __attribute__((ext_vector_type(8))) short;
using f32x4  = __attribute__((ext_vector_type(4))) float;

__device__ __forceinline__ unsigned short f2bf(float f) {
  unsigned int u = __float_as_uint(f);
  u += 0x7FFFu + ((u >> 16) & 1u);
  return (unsigned short)(u >> 16);
}
__device__ __forceinline__ float sigm(float x) { return 1.0f / (1.0f + __expf(-x)); }

#define MFMA16(A, Bf, C) __builtin_amdgcn_mfma_f32_16x16x32_bf16((A), (Bf), (C), 0, 0, 0)

// ----------------- prep kernels -----------------
__global__ void k_cvt_bf16(const float* __restrict__ src, unsigned short* __restrict__ dst, int n) {
  int i = (blockIdx.x * blockDim.x + threadIdx.x) * 4;
  if (i + 3 < n) {
    f32x4 v = *(const f32x4*)(src + i);
    *(ushort4*)(dst + i) = make_ushort4(f2bf(v[0]), f2bf(v[1]), f2bf(v[2]), f2bf(v[3]));
  }
}

__global__ void k_prep_small(const float* __restrict__ bih0, const float* __restrict__ bhh0,
                             float* __restrict__ b0s,
                             unsigned short* __restrict__ h1buf, unsigned short* __restrict__ h2buf) {
  int i = blockIdx.x * blockDim.x + threadIdx.x;  // 0 .. 262143
  if (i < 4096) b0s[i] = bih0[i] + bhh0[i];
  h1buf[i] = 0; h2buf[i] = 0;                     // 2*Bc*Hc = 262144 each
}

// ----------------- layer-0 bulk GEMM (no recurrence; f-gate dead) -----------------
// rows r = t*Bc + b over all 32768 (t,b); H0[r][j] bf16. xb is bf16 [B][T][E].
__global__ __launch_bounds__(512, 1) void k_l0(
    const unsigned short* __restrict__ xb, const unsigned short* __restrict__ W0,
    const float* __restrict__ b0s, unsigned short* __restrict__ H0)
{
  const int tid = threadIdx.x;
  const int lane = tid & 63, wid = tid >> 6;
  const int wM = wid >> 2, wN = wid & 3;           // 8 waves: 2(M) x 4(N)
  const int rowbase = blockIdx.x * 32 + wM * 16;   // 1024 x-tiles of 32 rows
  const int jbase   = blockIdx.y * 64 + wN * 16;   // 16 y-tiles of 64 hidden
  const int ri = lane & 15, kg = lane >> 4;

  const int r = rowbase + ri;
  const int t = r >> 7, b = r & (Bc - 1);
  const unsigned short* arow = xb + ((size_t)b * Tc + t) * Ec + kg * 8;

  const unsigned short* w0r = W0 + ((size_t)(0 * Hc + jbase + ri)) * Ec + kg * 8;
  const unsigned short* w2r = W0 + ((size_t)(2 * Hc + jbase + ri)) * Ec + kg * 8;
  const unsigned short* w3r = W0 + ((size_t)(3 * Hc + jbase + ri)) * Ec + kg * 8;

  f32x4 ai = {0,0,0,0}, ag = {0,0,0,0}, ao = {0,0,0,0};
#pragma unroll
  for (int kk = 0; kk < Ec / 32; ++kk) {
    bf16x8 a = *(const bf16x8*)(arow + kk * 32);
    ai = MFMA16(a, *(const bf16x8*)(w0r + kk * 32), ai);
    ag = MFMA16(a, *(const bf16x8*)(w2r + kk * 32), ag);
    ao = MFMA16(a, *(const bf16x8*)(w3r + kk * 32), ao);
  }
  const int j = jbase + ri;
  const float bi = b0s[j], bg = b0s[2 * Hc + j], bo = b0s[3 * Hc + j];
#pragma unroll
  for (int q = 0; q < 4; ++q) {
    const int rr = rowbase + kg * 4 + q;             // C row = (lane>>4)*4 + reg
    float c = sigm(ai[q] + bi) * tanhf(ag[q] + bg);  // c_prev = 0
    float h = sigm(ao[q] + bo) * tanhf(c);
    H0[(size_t)rr * Hc + j] = f2bf(h);
  }
}

// ----------------- recurrent cooperative kernel, weight-stationary in LDS -----------------
// 256 WGs x 512 thr (8 waves). WG bid: layer = bid>>7 (0 -> net layer1, 1 -> net layer2),
// j8-chunk = bid&127. LDS holds this WG's weights: 2 N-tiles x 64 k-steps, fragment-major
// (each frag = 64 lanes x 16B contiguous -> linear conflict-free ds_read_b128).
// Tile0 rows: [gate_i j0..j0+7 | gate_f j0..j0+7]; tile1: [gate_g | gate_o].
// c-state lives in registers for the whole time loop. One grid.sync per phase; 257 phases.
__global__ __launch_bounds__(512, 1) void k_rec(
    const unsigned short* H0,                        // [Tc*Bc][Hc] bf16 (upper half of d_out)
    const float* __restrict__ Wih, const float* __restrict__ Whh,  // [2][4096][1024] f32
    const float* __restrict__ bih, const float* __restrict__ bhh,  // [2][4096] f32
    unsigned short* h1buf, unsigned short* h2buf,    // [2][Bc][Hc] bf16 (phase parity dbuf)
    float* out)                                      // [Tc][Bc][Hc] f32 (lower d_out)
{
  __shared__ unsigned short Wlds[2 * 64 * 64 * 8];   // 128 KiB: [tile][kstep][lane][8]
  cg::grid_group grid = cg::this_grid();
  const int tid = threadIdx.x;
  const int lane = tid & 63, wid = tid >> 6;         // wave = m16 tile (8 waves = 128 rows)
  const int bid = blockIdx.x;
  const int layer = bid >> 7;
  const int j0 = (bid & 127) * 8;
  const int ri = lane & 15, kg = lane >> 4;

  // ---- prologue: weights fp32 -> bf16 into LDS, fragment-major ----
  const size_t lw = (size_t)layer * 4096 * 1024;
  for (int s = tid; s < 2 * 64 * 64; s += 512) {     // 8192 frag-slots of 16B
    const int l   = s & 63;                          // lane slot within frag
    const int kkg = (s >> 6) & 63;                   // global k-step (0..63)
    const int t   = s >> 12;                         // tile (0,1)
    const int rr  = l & 15;                          // B row within tile
    const int gate = t * 2 + (rr >> 3);
    const int R = gate * 1024 + j0 + (rr & 7);
    const int k = kkg * 32 + (l >> 4) * 8;
    const float* src = (k < 1024) ? (Wih + lw + (size_t)R * 1024 + k)
                                  : (Whh + lw + (size_t)R * 1024 + (k - 1024));
    f32x4 v0 = *(const f32x4*)src;
    f32x4 v1 = *(const f32x4*)(src + 4);
    ushort4* d = (ushort4*)(Wlds + (size_t)s * 8);
    d[0] = make_ushort4(f2bf(v0[0]), f2bf(v0[1]), f2bf(v0[2]), f2bf(v0[3]));
    d[1] = make_ushort4(f2bf(v1[0]), f2bf(v1[1]), f2bf(v1[2]), f2bf(v1[3]));
  }

  // per-lane biases: tile0 holds i (ri<8) / f (ri>=8); tile1 holds g / o
  const int jme = j0 + (ri & 7);
  const int g0 = (ri < 8) ? 0 : 1;
  const int g1 = (ri < 8) ? 2 : 3;
  const float bias0 = bih[layer * 4096 + g0 * 1024 + jme] + bhh[layer * 4096 + g0 * 1024 + jme];
  const float bias1 = bih[layer * 4096 + g1 * 1024 + jme] + bhh[layer * 4096 + g1 * 1024 + jme];

  float creg[4] = {0.f, 0.f, 0.f, 0.f};             // c-state, register-resident

  const unsigned short* lds0 = Wlds + (size_t)lane * 8;                 // tile0 frags
  const unsigned short* lds1 = Wlds + (size_t)64 * 64 * 8 + (size_t)lane * 8;  // tile1
  const int arow = wid * 16 + ri;                   // A row this lane loads

  __syncthreads();                                  // Wlds ready

  for (int p = 0; p <= Tc; ++p) {
    const int cur = p & 1, prev = cur ^ 1;
    const bool act = (layer == 0) ? (p < Tc) : (p >= 1);
    if (act) {
      const unsigned short* A1 = (layer == 0) ? (H0 + (size_t)p * Bc * Hc)
                                              : (h1buf + (size_t)prev * Bc * Hc);
      const unsigned short* A2 = (layer == 0) ? (h1buf + (size_t)prev * Bc * Hc)
                                              : (h2buf + (size_t)prev * Bc * Hc);
      const unsigned short* a1 = A1 + (size_t)arow * Hc + kg * 8;
      const unsigned short* a2 = A2 + (size_t)arow * Hc + kg * 8;

      f32x4 acc0 = {0,0,0,0}, acc1 = {0,0,0,0};
#pragma unroll
      for (int kk = 0; kk < 32; ++kk) {             // K 0..1023 (input h)
        bf16x8 a = *(const bf16x8*)(a1 + kk * 32);
        acc0 = MFMA16(a, *(const bf16x8*)(lds0 + kk * 512), acc0);
        acc1 = MFMA16(a, *(const bf16x8*)(lds1 + kk * 512), acc1);
      }
#pragma unroll
      for (int kk = 32; kk < 64; ++kk) {            // K 1024..2047 (own h prev)
        bf16x8 a = *(const bf16x8*)(a2 + (kk - 32) * 32);
        acc0 = MFMA16(a, *(const bf16x8*)(lds0 + kk * 512), acc0);
        acc1 = MFMA16(a, *(const bf16x8*)(lds1 + kk * 512), acc1);
      }

      // cell update: lanes (ri, ri+8) pair-exchange i<->f and g<->o
      float* po = out + (size_t)(p - 1) * Bc * Hc;
      unsigned short* hb = (layer == 0 ? h1buf : h2buf) + (size_t)cur * Bc * Hc;
      const bool lo = (ri < 8);
#pragma unroll
      for (int q = 0; q < 4; ++q) {
        float x0 = acc0[q] + bias0;
        float x1 = acc1[q] + bias1;
        float p0 = __shfl_xor(x0, 8);
        float p1 = __shfl_xor(x1, 8);
        float gi = lo ? x0 : p0;
        float gf = lo ? p0 : x0;
        float gg = lo ? x1 : p1;
        float go = lo ? p1 : x1;
        float cn = sigm(gf) * creg[q] + sigm(gi) * tanhf(gg);
        float hn = sigm(go) * tanhf(cn);
        creg[q] = cn;
        const int rr = wid * 16 + kg * 4 + q;
        if (lo) {
          hb[(size_t)rr * Hc + jme] = f2bf(hn);
          if (layer == 1) po[(size_t)rr * Hc + jme] = hn;
        }
      }
    }
    grid.sync();
  }
}

// ----------------- launcher -----------------
extern "C" void kernel_launch(void* const* d_in, const int* in_sizes, int n_in,
                              void* d_out, int out_size, void* d_ws, size_t ws_size,
                              hipStream_t stream) {
  const float* x     = (const float*)d_in[0];
  const float* W_ih0 = (const float*)d_in[1];
  // d_in[2] = W_hh0 (unused: layer-0 state is always zero)
  const float* b_ih0 = (const float*)d_in[3];
  const float* b_hh0 = (const float*)d_in[4];
  const float* W_ihr = (const float*)d_in[5];
  const float* W_hhr = (const float*)d_in[6];
  const float* b_ihr = (const float*)d_in[7];
  const float* b_hhr = (const float*)d_in[8];

  char* ws = (char*)d_ws;
  constexpr size_t W0B_OFF = 0;                                  // 4096*512*2   = 4 MB
  constexpr size_t XB_OFF  = W0B_OFF + (size_t)4096 * 512 * 2;   // 128*256*512*2 = 32 MB
  constexpr size_t B0S_OFF = XB_OFF + (size_t)Bc * Tc * Ec * 2;  // 16 KB
  constexpr size_t H1B_OFF = B0S_OFF + 4096 * 4;                 // 2*128*1024*2 = 512 KB
  constexpr size_t H2B_OFF = H1B_OFF + (size_t)2 * Bc * Hc * 2;

  unsigned short* W0b = (unsigned short*)(ws + W0B_OFF);
  unsigned short* xb  = (unsigned short*)(ws + XB_OFF);
  float* b0s = (float*)(ws + B0S_OFF);
  unsigned short* h1buf = (unsigned short*)(ws + H1B_OFF);
  unsigned short* h2buf = (unsigned short*)(ws + H2B_OFF);

  // H0 (bf16 [T][B][H], 64 MB) lives in the upper half of d_out; out fp32 fills
  // from the front. out[t'] (written at phase t'+1) only touches H0[q] bytes for
  // phases far beyond H0[q]'s last read (phase q) — verified byte-exact.
  unsigned short* H0 = (unsigned short*)d_out + (size_t)Tc * Bc * Hc;
  float* out = (float*)d_out;

  int n0 = 4096 * 512;
  k_cvt_bf16<<<n0 / 1024, 256, 0, stream>>>(W_ih0, W0b, n0);
  int nx = Bc * Tc * Ec;
  k_cvt_bf16<<<nx / 1024, 256, 0, stream>>>(x, xb, nx);
  k_prep_small<<<1024, 256, 0, stream>>>(b_ih0, b_hh0, b0s, h1buf, h2buf);
  k_l0<<<dim3(1024, 16), 512, 0, stream>>>(xb, W0b, b0s, H0);

  const float* Wih = W_ihr; const float* Whh = W_hhr;
  const float* bih = b_ihr; const float* bhh = b_hhr;
  void* kargs[] = { &H0, &Wih, &Whh, &bih, &bhh, &h1buf, &h2buf, &out };
  hipLaunchCooperativeKernel((void*)k_rec, dim3(256), dim3(512), kargs, 0, stream);
}

// Round 3
// 8150.764 us; speedup vs baseline: 2.2548x; 1.5028x over previous
//
#include <hip/hip_runtime.h>
#include <hip/hip_cooperative_groups.h>

static constexpr int Bc = 128;   // batch
static constexpr int Tc = 256;   // timesteps
static constexpr int Ec = 512;   // input embed
static constexpr int Hc = 1024;  // hidden

using bf16x8 = __attribute__((ext_vector_type(8))) short;
using f32x4  = __attribute__((ext_vector_type(4))) float;

__device__ __forceinline__ unsigned short f2bf(float f) {
  unsigned int u = __float_as_uint(f);
  u += 0x7FFFu + ((u >> 16) & 1u);
  return (unsigned short)(u >> 16);
}
__device__ __forceinline__ float sigm(float x) { return 1.0f / (1.0f + __expf(-x)); }

#define MFMA16(A, Bf, C) __builtin_amdgcn_mfma_f32_16x16x32_bf16((A), (Bf), (C), 0, 0, 0)

__device__ __forceinline__ void wait_ge(int* ctr, int val) {
  while (__hip_atomic_load(ctr, __ATOMIC_ACQUIRE, __HIP_MEMORY_SCOPE_AGENT) < val)
    __builtin_amdgcn_s_sleep(1);
}
__device__ __forceinline__ void signal(int* ctr) {
  __hip_atomic_fetch_add(ctr, 1, __ATOMIC_RELEASE, __HIP_MEMORY_SCOPE_AGENT);
}

// ----------------- prep kernels -----------------
__global__ void k_cvt_bf16(const float* __restrict__ src, unsigned short* __restrict__ dst, int n) {
  int i = (blockIdx.x * blockDim.x + threadIdx.x) * 4;
  if (i + 3 < n) {
    f32x4 v = *(const f32x4*)(src + i);
    *(ushort4*)(dst + i) = make_ushort4(f2bf(v[0]), f2bf(v[1]), f2bf(v[2]), f2bf(v[3]));
  }
}

__global__ void k_prep_small(const float* __restrict__ bih0, const float* __restrict__ bhh0,
                             float* __restrict__ b0s,
                             unsigned short* __restrict__ h1buf, unsigned short* __restrict__ h2buf,
                             int* __restrict__ d1, int* __restrict__ d2) {
  int i = blockIdx.x * blockDim.x + threadIdx.x;  // grid covers 4*Bc*Hc = 524288
  if (i < 4096) b0s[i] = bih0[i] + bhh0[i];
  h1buf[i] = 0; h2buf[i] = 0;
  if (i < Tc) { d1[i] = 0; d2[i] = 0; }
}

// ----------------- layer-0 bulk GEMM (no recurrence; f-gate dead) -----------------
__global__ __launch_bounds__(512, 1) void k_l0(
    const unsigned short* __restrict__ xb, const unsigned short* __restrict__ W0,
    const float* __restrict__ b0s, unsigned short* __restrict__ H0)
{
  const int tid = threadIdx.x;
  const int lane = tid & 63, wid = tid >> 6;
  const int wM = wid >> 2, wN = wid & 3;           // 8 waves: 2(M) x 4(N)
  const int rowbase = blockIdx.x * 32 + wM * 16;
  const int jbase   = blockIdx.y * 64 + wN * 16;
  const int ri = lane & 15, kg = lane >> 4;

  const int r = rowbase + ri;
  const int t = r >> 7, b = r & (Bc - 1);
  const unsigned short* arow = xb + ((size_t)b * Tc + t) * Ec + kg * 8;

  const unsigned short* w0r = W0 + ((size_t)(0 * Hc + jbase + ri)) * Ec + kg * 8;
  const unsigned short* w2r = W0 + ((size_t)(2 * Hc + jbase + ri)) * Ec + kg * 8;
  const unsigned short* w3r = W0 + ((size_t)(3 * Hc + jbase + ri)) * Ec + kg * 8;

  f32x4 ai = {0,0,0,0}, ag = {0,0,0,0}, ao = {0,0,0,0};
#pragma unroll
  for (int kk = 0; kk < Ec / 32; ++kk) {
    bf16x8 a = *(const bf16x8*)(arow + kk * 32);
    ai = MFMA16(a, *(const bf16x8*)(w0r + kk * 32), ai);
    ag = MFMA16(a, *(const bf16x8*)(w2r + kk * 32), ag);
    ao = MFMA16(a, *(const bf16x8*)(w3r + kk * 32), ao);
  }
  const int j = jbase + ri;
  const float bi = b0s[j], bg = b0s[2 * Hc + j], bo = b0s[3 * Hc + j];
#pragma unroll
  for (int q = 0; q < 4; ++q) {
    const int rr = rowbase + kg * 4 + q;
    float c = sigm(ai[q] + bi) * tanhf(ag[q] + bg);
    float h = sigm(ao[q] + bo) * tanhf(c);
    H0[(size_t)rr * Hc + j] = f2bf(h);
  }
}

// ----------------- recurrent kernel: weight-stationary LDS + flag-pipelined phases ----------
// 256 WGs x 512 thr (8 waves), 1 WG/CU. WGs 0..127: layer1; 128..255: layer2.
// No grid.sync: per-phase completion counters d1[p], d2[s] (release/acquire, agent scope).
// State buffers are 4-phase deep; buffer-recycle waits bound skew to <= 4 phases.
// Each layer computes its dependency-free K-half BEFORE waiting, hiding flag latency.
__global__ __launch_bounds__(512, 1) void k_rec(
    const unsigned short* H0,                        // [Tc*Bc][Hc] bf16 (upper half of d_out)
    const float* __restrict__ Wih, const float* __restrict__ Whh,  // [2][4096][1024] f32
    const float* __restrict__ bih, const float* __restrict__ bhh,  // [2][4096] f32
    unsigned short* h1buf, unsigned short* h2buf,    // [4][Bc][Hc] bf16
    int* d1, int* d2,                                // [Tc] phase-completion counters
    float* out)                                      // [Tc][Bc][Hc] f32 (lower d_out)
{
  __shared__ unsigned short Wlds[2 * 64 * 64 * 8];   // 128 KiB: [tile][kstep][lane][8]
  const int tid = threadIdx.x;
  const int lane = tid & 63, wid = tid >> 6;
  const int bid = blockIdx.x;
  const int layer = bid >> 7;
  const int j0 = (bid & 127) * 8;
  const int ri = lane & 15, kg = lane >> 4;

  // ---- prologue: weights fp32 -> bf16 into LDS, fragment-major ----
  const size_t lw = (size_t)layer * 4096 * 1024;
  for (int s = tid; s < 2 * 64 * 64; s += 512) {
    const int l   = s & 63;
    const int kkg = (s >> 6) & 63;
    const int t   = s >> 12;
    const int rr  = l & 15;
    const int gate = t * 2 + (rr >> 3);
    const int R = gate * 1024 + j0 + (rr & 7);
    const int k = kkg * 32 + (l >> 4) * 8;
    const float* src = (k < 1024) ? (Wih + lw + (size_t)R * 1024 + k)
                                  : (Whh + lw + (size_t)R * 1024 + (k - 1024));
    f32x4 v0 = *(const f32x4*)src;
    f32x4 v1 = *(const f32x4*)(src + 4);
    ushort4* d = (ushort4*)(Wlds + (size_t)s * 8);
    d[0] = make_ushort4(f2bf(v0[0]), f2bf(v0[1]), f2bf(v0[2]), f2bf(v0[3]));
    d[1] = make_ushort4(f2bf(v1[0]), f2bf(v1[1]), f2bf(v1[2]), f2bf(v1[3]));
  }

  const int jme = j0 + (ri & 7);
  const int g0 = (ri < 8) ? 0 : 1;                  // tile0: i | f
  const int g1 = (ri < 8) ? 2 : 3;                  // tile1: g | o
  const float bias0 = bih[layer * 4096 + g0 * 1024 + jme] + bhh[layer * 4096 + g0 * 1024 + jme];
  const float bias1 = bih[layer * 4096 + g1 * 1024 + jme] + bhh[layer * 4096 + g1 * 1024 + jme];

  float creg[4] = {0.f, 0.f, 0.f, 0.f};

  const unsigned short* lds0 = Wlds + (size_t)lane * 8;
  const unsigned short* lds1 = Wlds + (size_t)64 * 64 * 8 + (size_t)lane * 8;
  const int arow = wid * 16 + ri;
  const bool lo = (ri < 8);

  __syncthreads();                                  // Wlds ready

  if (layer == 0) {
    // ---------------- layer 1: h1(p) = cell(H0(p), h1(p-1)) ----------------
    for (int p = 0; p < Tc; ++p) {
      // free half: A1 = H0(p), K 0..1023
      const unsigned short* a1 = H0 + (size_t)p * Bc * Hc + (size_t)arow * Hc + kg * 8;
      f32x4 acc0 = {0,0,0,0}, acc1 = {0,0,0,0};
#pragma unroll
      for (int kk = 0; kk < 32; ++kk) {
        bf16x8 a = *(const bf16x8*)(a1 + kk * 32);
        acc0 = MFMA16(a, *(const bf16x8*)(lds0 + kk * 512), acc0);
        acc1 = MFMA16(a, *(const bf16x8*)(lds1 + kk * 512), acc1);
      }
      // gated half: A2 = h1(p-1)
      if (tid == 0 && p >= 1) wait_ge(d1 + p - 1, 128);
      __syncthreads();
      const unsigned short* a2 = h1buf + (size_t)((p - 1) & 3) * Bc * Hc + (size_t)arow * Hc + kg * 8;
#pragma unroll
      for (int kk = 32; kk < 64; ++kk) {
        bf16x8 a = *(const bf16x8*)(a2 + (kk - 32) * 32);
        acc0 = MFMA16(a, *(const bf16x8*)(lds0 + kk * 512), acc0);
        acc1 = MFMA16(a, *(const bf16x8*)(lds1 + kk * 512), acc1);
      }
      // cell epilogue into registers
      float hn[4];
#pragma unroll
      for (int q = 0; q < 4; ++q) {
        float x0 = acc0[q] + bias0;
        float x1 = acc1[q] + bias1;
        float p0 = __shfl_xor(x0, 8);
        float p1 = __shfl_xor(x1, 8);
        float gi = lo ? x0 : p0;
        float gf = lo ? p0 : x0;
        float gg = lo ? x1 : p1;
        float go = lo ? p1 : x1;
        float cn = sigm(gf) * creg[q] + sigm(gi) * tanhf(gg);
        hn[q] = sigm(go) * tanhf(cn);
        creg[q] = cn;
      }
      // recycle wait: h1buf[p&3] last read by layer-2 step p-4
      if (tid == 0 && p >= 4) wait_ge(d2 + p - 4, 128);
      __syncthreads();
      unsigned short* hb = h1buf + (size_t)(p & 3) * Bc * Hc;
      if (lo) {
#pragma unroll
        for (int q = 0; q < 4; ++q) {
          const int rr = wid * 16 + kg * 4 + q;
          hb[(size_t)rr * Hc + jme] = f2bf(hn[q]);
        }
      }
      __syncthreads();
      if (tid == 0) signal(d1 + p);
    }
  } else {
    // ---------------- layer 2: h2(s) = cell(h1(s), h2(s-1)) ----------------
    for (int s = 0; s < Tc; ++s) {
      // own-chain half first: A2 = h2(s-1), K 1024..2047
      if (tid == 0 && s >= 1) wait_ge(d2 + s - 1, 128);
      __syncthreads();
      const unsigned short* a2 = h2buf + (size_t)((s - 1) & 3) * Bc * Hc + (size_t)arow * Hc + kg * 8;
      f32x4 acc0 = {0,0,0,0}, acc1 = {0,0,0,0};
#pragma unroll
      for (int kk = 32; kk < 64; ++kk) {
        bf16x8 a = *(const bf16x8*)(a2 + (kk - 32) * 32);
        acc0 = MFMA16(a, *(const bf16x8*)(lds0 + kk * 512), acc0);
        acc1 = MFMA16(a, *(const bf16x8*)(lds1 + kk * 512), acc1);
      }
      // cross-layer half: A1 = h1(s)
      if (tid == 0) wait_ge(d1 + s, 128);
      __syncthreads();
      const unsigned short* a1 = h1buf + (size_t)(s & 3) * Bc * Hc + (size_t)arow * Hc + kg * 8;
#pragma unroll
      for (int kk = 0; kk < 32; ++kk) {
        bf16x8 a = *(const bf16x8*)(a1 + kk * 32);
        acc0 = MFMA16(a, *(const bf16x8*)(lds0 + kk * 512), acc0);
        acc1 = MFMA16(a, *(const bf16x8*)(lds1 + kk * 512), acc1);
      }
      // cell epilogue + stores (recycle of h2buf[s&3] is safe via d2[s-1] chain)
      unsigned short* hb = h2buf + (size_t)(s & 3) * Bc * Hc;
      float* po = out + (size_t)s * Bc * Hc;
#pragma unroll
      for (int q = 0; q < 4; ++q) {
        float x0 = acc0[q] + bias0;
        float x1 = acc1[q] + bias1;
        float p0 = __shfl_xor(x0, 8);
        float p1 = __shfl_xor(x1, 8);
        float gi = lo ? x0 : p0;
        float gf = lo ? p0 : x0;
        float gg = lo ? x1 : p1;
        float go = lo ? p1 : x1;
        float cn = sigm(gf) * creg[q] + sigm(gi) * tanhf(gg);
        float hnv = sigm(go) * tanhf(cn);
        creg[q] = cn;
        const int rr = wid * 16 + kg * 4 + q;
        if (lo) {
          hb[(size_t)rr * Hc + jme] = f2bf(hnv);
          po[(size_t)rr * Hc + jme] = hnv;
        }
      }
      __syncthreads();
      if (tid == 0) signal(d2 + s);
    }
  }
}

// ----------------- launcher -----------------
extern "C" void kernel_launch(void* const* d_in, const int* in_sizes, int n_in,
                              void* d_out, int out_size, void* d_ws, size_t ws_size,
                              hipStream_t stream) {
  const float* x     = (const float*)d_in[0];
  const float* W_ih0 = (const float*)d_in[1];
  // d_in[2] = W_hh0 (unused: layer-0 state is always zero)
  const float* b_ih0 = (const float*)d_in[3];
  const float* b_hh0 = (const float*)d_in[4];
  const float* W_ihr = (const float*)d_in[5];
  const float* W_hhr = (const float*)d_in[6];
  const float* b_ihr = (const float*)d_in[7];
  const float* b_hhr = (const float*)d_in[8];

  char* ws = (char*)d_ws;
  constexpr size_t W0B_OFF = 0;                                  // 4 MB
  constexpr size_t XB_OFF  = W0B_OFF + (size_t)4096 * 512 * 2;   // 32 MB
  constexpr size_t B0S_OFF = XB_OFF + (size_t)Bc * Tc * Ec * 2;  // 16 KB
  constexpr size_t H1B_OFF = B0S_OFF + 4096 * 4;                 // 4*128*1024*2 = 1 MB
  constexpr size_t H2B_OFF = H1B_OFF + (size_t)4 * Bc * Hc * 2;  // 1 MB
  constexpr size_t D1_OFF  = H2B_OFF + (size_t)4 * Bc * Hc * 2;  // 1 KB
  constexpr size_t D2_OFF  = D1_OFF + 1024;

  unsigned short* W0b = (unsigned short*)(ws + W0B_OFF);
  unsigned short* xb  = (unsigned short*)(ws + XB_OFF);
  float* b0s = (float*)(ws + B0S_OFF);
  unsigned short* h1buf = (unsigned short*)(ws + H1B_OFF);
  unsigned short* h2buf = (unsigned short*)(ws + H2B_OFF);
  int* d1 = (int*)(ws + D1_OFF);
  int* d2 = (int*)(ws + D2_OFF);

  // H0 (bf16 [T][B][H], 64 MB) lives in the upper half of d_out. Aliasing with the
  // fp32 out[] writes was re-verified under the flag pipeline (skew-bounded): out[s]
  // overlaps H0[q] only for q <= 2(s-128)+1, and layer-2 step s starts only after
  // d1[s] (layer-1 finished reading H0(s)), with s >= q+1 for all overlapping q.
  unsigned short* H0 = (unsigned short*)d_out + (size_t)Tc * Bc * Hc;
  float* out = (float*)d_out;

  int n0 = 4096 * 512;
  k_cvt_bf16<<<n0 / 1024, 256, 0, stream>>>(W_ih0, W0b, n0);
  int nx = Bc * Tc * Ec;
  k_cvt_bf16<<<nx / 1024, 256, 0, stream>>>(x, xb, nx);
  k_prep_small<<<2048, 256, 0, stream>>>(b_ih0, b_hh0, b0s, h1buf, h2buf, d1, d2);
  k_l0<<<dim3(1024, 16), 512, 0, stream>>>(xb, W0b, b0s, H0);

  const float* Wih = W_ihr; const float* Whh = W_hhr;
  const float* bih = b_ihr; const float* bhh = b_hhr;
  void* kargs[] = { &H0, &Wih, &Whh, &bih, &bhh, &h1buf, &h2buf, &d1, &d2, &out };
  hipLaunchCooperativeKernel((void*)k_rec, dim3(256), dim3(512), kargs, 0, stream);
}